// Round 7
// baseline (578.340 us; speedup 1.0000x reference)
//
#include <hip/hip_runtime.h>

// TransformerBlock: B=8, S=1024, D=1024, H=16, HD=64
// LN1 -> QKV GEMM(256q) -> causal flash attn -> proj(+resid,128q) -> LN2
//     -> MLP1(+gelu,256q) -> MLP2(+resid -> d_out,128q)
// 256q GEMM: 256x256 tile, 8 waves, counted-vmcnt double-buffer (raw s_barrier,
//            never drains vmcnt to 0 in the main loop). 128q GEMM: validated m97-style.

#define DEV static __device__ __forceinline__

typedef __attribute__((ext_vector_type(8))) __bf16 bf16x8;
typedef __attribute__((ext_vector_type(4))) float f32x4;

DEV ushort f2bf(float f) {
  union { float f; unsigned u; } c; c.f = f;
  unsigned r = (c.u + 0x7FFFu + ((c.u >> 16) & 1u)) >> 16;
  return (ushort)r;
}

DEV float geluf(float v) {
  return 0.5f * v * (1.0f + erff(v * 0.70710678118654752f));
}

DEV void gload16(const ushort* g, ushort* l) {
  __builtin_amdgcn_global_load_lds(
      (const __attribute__((address_space(1))) void*)g,
      (__attribute__((address_space(3))) void*)l, 16, 0, 0);
}

// ---------------- LayerNorm (f32 in -> bf16 out), one block per row ----------------
__global__ __launch_bounds__(256)
void ln_bf16_kernel(const float* __restrict__ x, const float* __restrict__ g,
                    const float* __restrict__ bb, ushort* __restrict__ out)
{
  const int row = blockIdx.x, tid = threadIdx.x;
  const float4 v = ((const float4*)x)[row * 256 + tid];
  float s = v.x + v.y + v.z + v.w;
  float sq = v.x * v.x + v.y * v.y + v.z * v.z + v.w * v.w;
#pragma unroll
  for (int off = 32; off >= 1; off >>= 1) {
    s += __shfl_xor(s, off, 64);
    sq += __shfl_xor(sq, off, 64);
  }
  __shared__ float ps[4], pq[4];
  if ((tid & 63) == 0) { ps[tid >> 6] = s; pq[tid >> 6] = sq; }
  __syncthreads();
  s = ps[0] + ps[1] + ps[2] + ps[3];
  sq = pq[0] + pq[1] + pq[2] + pq[3];
  const float mu = s * (1.0f / 1024.0f);
  const float rstd = rsqrtf(sq * (1.0f / 1024.0f) - mu * mu + 1e-5f);
  const float4 gv = ((const float4*)g)[tid];
  const float4 bv = ((const float4*)bb)[tid];
  ushort4 o;
  o.x = f2bf((v.x - mu) * rstd * gv.x + bv.x);
  o.y = f2bf((v.y - mu) * rstd * gv.y + bv.y);
  o.z = f2bf((v.z - mu) * rstd * gv.z + bv.z);
  o.w = f2bf((v.w - mu) * rstd * gv.w + bv.w);
  ((ushort4*)out)[row * 256 + tid] = o;
}

// ---------------- transpose + f32->bf16: out[n*K+k] = bf16(in[k*N+n]) ----------------
__global__ __launch_bounds__(256)
void tcvt_kernel(const float* __restrict__ in, ushort* __restrict__ out, int K, int N)
{
  __shared__ float tile[32][33];
  const int tx = threadIdx.x & 31, ty = threadIdx.x >> 5;  // ty 0..7
  const int n0 = blockIdx.x * 32, k0 = blockIdx.y * 32;
#pragma unroll
  for (int j = 0; j < 4; ++j)
    tile[ty + j * 8][tx] = in[(size_t)(k0 + ty + j * 8) * N + n0 + tx];
  __syncthreads();
#pragma unroll
  for (int j = 0; j < 4; ++j)
    out[(size_t)(n0 + ty + j * 8) * K + k0 + tx] = f2bf(tile[tx][ty + j * 8]);
}

// ---------------- V^T extraction: VT[(bh*64+hd)*1024 + s] = qkv[b,s, 2048+h*64+hd] ----
__global__ __launch_bounds__(256)
void vtr_kernel(const ushort* __restrict__ qkv, ushort* __restrict__ VT)
{
  __shared__ ushort tile[64][72];
  const int tid = threadIdx.x;
  const int bh = blockIdx.x, sb = blockIdx.y;
  const int b = bh >> 4, h = bh & 15;
  const int s0 = sb * 64;
#pragma unroll
  for (int it = 0; it < 2; ++it) {
    const int idx = it * 256 + tid;
    const int r = idx >> 3, hc = (idx & 7) * 8;
    *(int4*)&tile[r][hc] =
        *(const int4*)(qkv + ((size_t)b * 1024 + s0 + r) * 3072 + 2048 + h * 64 + hc);
  }
  __syncthreads();
#pragma unroll
  for (int it = 0; it < 2; ++it) {
    const int idx = it * 256 + tid;
    const int hd = idx >> 3, sc = (idx & 7) * 8;
    union { int4 v; ushort u[8]; } o;
#pragma unroll
    for (int j = 0; j < 8; ++j) o.u[j] = tile[sc + j][hd];
    *(int4*)(VT + ((size_t)bh * 64 + hd) * 1024 + s0 + sc) = o.v;
  }
}

// ---------------- 128x128 GEMM (validated m97 structure), EPI 2 only ----------------
// C[M,N] = A[M,K](bf16) * Bt[N,K]^T + bias + resid, f32 out.
template<int EPI>
__global__ __launch_bounds__(256)
void gemm_bf16(const ushort* __restrict__ A, const ushort* __restrict__ Bt,
               const float* __restrict__ bias, const float* __restrict__ resid,
               void* __restrict__ outp, int M, int N, int K)
{
  __shared__ ushort Asl[128 * 64];
  __shared__ ushort Bsl[128 * 64];
  const int tid = threadIdx.x;
  const int lane = tid & 63, w = tid >> 6;
  const int wm = w >> 1, wn = w & 1;
  const int grp = lane >> 4, r16 = lane & 15;
  const int bm = blockIdx.y * 128, bn = blockIdx.x * 128;

  const int lrow = lane >> 3;                      // 0..7
  const int uswz = ((lane & 7) ^ lrow) * 8;        // pre-swizzled k-unit (ushort offs)
  const ushort* pa = A  + (size_t)(bm + w * 32 + lrow) * K + uswz;
  const ushort* pb = Bt + (size_t)(bn + w * 32 + lrow) * K + uswz;

  f32x4 acc[4][4] = {};

  for (int k0 = 0; k0 < K; k0 += 64) {
    __syncthreads();
#pragma unroll
    for (int i = 0; i < 4; ++i) {
      gload16(pa + (size_t)(i * 8) * K + k0, &Asl[(w * 32 + i * 8) * 64]);
      gload16(pb + (size_t)(i * 8) * K + k0, &Bsl[(w * 32 + i * 8) * 64]);
    }
    __syncthreads();
#pragma unroll
    for (int ks = 0; ks < 2; ++ks) {
      bf16x8 af[4], bfr[4];
#pragma unroll
      for (int m = 0; m < 4; ++m) {
        const int r = wm * 64 + m * 16 + r16;
        af[m] = *(const bf16x8*)&Asl[r * 64 + ((ks * 4 + grp) ^ (r16 & 7)) * 8];
      }
#pragma unroll
      for (int n = 0; n < 4; ++n) {
        const int r = wn * 64 + n * 16 + r16;
        bfr[n] = *(const bf16x8*)&Bsl[r * 64 + ((ks * 4 + grp) ^ (r16 & 7)) * 8];
      }
#pragma unroll
      for (int m = 0; m < 4; ++m)
#pragma unroll
        for (int n = 0; n < 4; ++n)
          acc[m][n] = __builtin_amdgcn_mfma_f32_16x16x32_bf16(af[m], bfr[n], acc[m][n], 0, 0, 0);
    }
  }

#pragma unroll
  for (int n = 0; n < 4; ++n) {
    const int col = bn + wn * 64 + n * 16 + r16;
    const float bval = bias[col];
#pragma unroll
    for (int m = 0; m < 4; ++m) {
      const int row0 = bm + wm * 64 + m * 16 + grp * 4;
#pragma unroll
      for (int r = 0; r < 4; ++r) {
        const size_t idx = (size_t)(row0 + r) * N + col;
        float v = acc[m][n][r] + bval;
        if (EPI == 1) v = geluf(v);
        if (EPI == 2) ((float*)outp)[idx] = v + resid[idx];
        else          ((ushort*)outp)[idx] = f2bf(v);
      }
    }
  }
}

// ---------------- 256x256 GEMM, counted-vmcnt double-buffer ----------------
// 512 threads = 8 waves (2M x 4N), per-wave output 128x64, BK=64.
// LDS 128 KB dynamic: [buf][ A 256x64 | B 256x64 ].
// Pipeline: stage t+2 issued after compute-t barrier; top-of-iter waits
// vmcnt(8) (tile t's 8 loads) leaving tile t+1's 8 in flight. Raw s_barrier
// (no vmcnt(0) drain). Swizzle identical to 128q kernel (rule-21 involution).
// EPI 0: bf16 out (+bias).  EPI 1: bf16 out, gelu(+bias).
template<int EPI>
__global__ __launch_bounds__(512, 2)
void gemm256(const ushort* __restrict__ A, const ushort* __restrict__ Bt,
             const float* __restrict__ bias, void* __restrict__ outp,
             int M, int N, int K)
{
  extern __shared__ ushort sm[];                   // 2 * (16384 + 16384) ushorts
  const int tid = threadIdx.x;
  const int lane = tid & 63, w = tid >> 6;         // wave 0..7
  const int wm = w >> 2, wn = w & 3;               // 2 x 4
  const int grp = lane >> 4, r16 = lane & 15;
  const int bm = blockIdx.y * 256, bn = blockIdx.x * 256;

  // staging: wave w owns rows [w*32, w*32+32) of each 256-row tile
  const int lrow = lane >> 3;                      // 0..7
  const int uswz = ((lane & 7) ^ lrow) * 8;        // pre-swizzled k-unit
  const ushort* pa = A  + (size_t)(bm + w * 32 + lrow) * K + uswz;
  const ushort* pb = Bt + (size_t)(bn + w * 32 + lrow) * K + uswz;

  const int nt = K >> 6;
  f32x4 acc[8][4] = {};

  // prologue: issue tiles 0 and 1 (8 loads each)
#pragma unroll
  for (int i = 0; i < 4; ++i) {
    gload16(pa + (size_t)(i * 8) * K, &sm[(w * 32 + i * 8) * 64]);
    gload16(pb + (size_t)(i * 8) * K, &sm[16384 + (w * 32 + i * 8) * 64]);
  }
#pragma unroll
  for (int i = 0; i < 4; ++i) {
    gload16(pa + (size_t)(i * 8) * K + 64, &sm[32768 + (w * 32 + i * 8) * 64]);
    gload16(pb + (size_t)(i * 8) * K + 64, &sm[32768 + 16384 + (w * 32 + i * 8) * 64]);
  }

  for (int t = 0; t < nt; ++t) {
    if (t + 1 < nt) { asm volatile("s_waitcnt vmcnt(8)" ::: "memory"); }
    else            { asm volatile("s_waitcnt vmcnt(0)" ::: "memory"); }
    __builtin_amdgcn_s_barrier();
    __builtin_amdgcn_sched_barrier(0);
    const ushort* as = sm + (t & 1) * 32768;
    const ushort* bs = as + 16384;
#pragma unroll
    for (int ks = 0; ks < 2; ++ks) {
      bf16x8 af[8], bfr[4];
#pragma unroll
      for (int mf = 0; mf < 8; ++mf) {
        const int r = wm * 128 + mf * 16 + r16;
        af[mf] = *(const bf16x8*)&as[r * 64 + ((ks * 4 + grp) ^ (r16 & 7)) * 8];
      }
#pragma unroll
      for (int nf = 0; nf < 4; ++nf) {
        const int r = wn * 64 + nf * 16 + r16;
        bfr[nf] = *(const bf16x8*)&bs[r * 64 + ((ks * 4 + grp) ^ (r16 & 7)) * 8];
      }
      __builtin_amdgcn_s_setprio(1);
#pragma unroll
      for (int mf = 0; mf < 8; ++mf)
#pragma unroll
        for (int nf = 0; nf < 4; ++nf)
          acc[mf][nf] = __builtin_amdgcn_mfma_f32_16x16x32_bf16(af[mf], bfr[nf], acc[mf][nf], 0, 0, 0);
      __builtin_amdgcn_s_setprio(0);
    }
    asm volatile("s_waitcnt lgkmcnt(0)" ::: "memory");  // my LDS reads done
    __builtin_amdgcn_sched_barrier(0);
    __builtin_amdgcn_s_barrier();                       // all waves' reads done
    __builtin_amdgcn_sched_barrier(0);
    if (t + 2 < nt) {                                   // refill freed buffer
      const int k0 = (t + 2) * 64;
      ushort* za = sm + (t & 1) * 32768;
      ushort* zb = za + 16384;
#pragma unroll
      for (int i = 0; i < 4; ++i) {
        gload16(pa + (size_t)(i * 8) * K + k0, &za[(w * 32 + i * 8) * 64]);
        gload16(pb + (size_t)(i * 8) * K + k0, &zb[(w * 32 + i * 8) * 64]);
      }
    }
  }

#pragma unroll
  for (int nf = 0; nf < 4; ++nf) {
    const int col = bn + wn * 64 + nf * 16 + r16;
    const float bval = bias[col];
#pragma unroll
    for (int mf = 0; mf < 8; ++mf) {
      const int row0 = bm + wm * 128 + mf * 16 + grp * 4;
#pragma unroll
      for (int r = 0; r < 4; ++r) {
        const size_t idx = (size_t)(row0 + r) * N + col;
        float v = acc[mf][nf][r] + bval;
        if (EPI == 1) v = geluf(v);
        ((ushort*)outp)[idx] = f2bf(v);
      }
    }
  }
}

// ---------------- Causal flash attention (unchanged, validated) ----------------
__global__ __launch_bounds__(256)
void attn_kernel(const ushort* __restrict__ qkv, const ushort* __restrict__ VT,
                 ushort* __restrict__ out)
{
  __shared__ ushort Ks[64 * 64];
  __shared__ ushort Vs[64 * 64];
  __shared__ ushort Ps[4][16][72];
  const int tid = threadIdx.x, lane = tid & 63, w = tid >> 6;
  const int grp = lane >> 4, r16 = lane & 15;
  const int qb = 15 - blockIdx.x;
  const int bh = blockIdx.y;
  const int b = bh >> 4, h = bh & 15;
  const size_t rowbase = (size_t)b * 1024;
  const int q0 = qb * 64 + w * 16;

  bf16x8 qf[2];
  {
    const ushort* qp = qkv + (rowbase + q0 + r16) * 3072 + h * 64;
    qf[0] = *(const bf16x8*)(qp + grp * 8);
    qf[1] = *(const bf16x8*)(qp + 32 + grp * 8);
  }

  const int lrow = lane >> 3;
  const int uswz = ((lane & 7) ^ lrow) * 8;
  const ushort* kstg = qkv + (rowbase + w * 16 + lrow) * 3072 + 1024 + h * 64 + uswz;
  const ushort* vstg = VT + ((size_t)bh * 64 + w * 16 + lrow) * 1024 + uswz;

  f32x4 o[4] = {};
  float mrow[4] = {-1e30f, -1e30f, -1e30f, -1e30f};
  float lsum[4] = {0.f, 0.f, 0.f, 0.f};

  for (int kb = 0; kb <= qb; ++kb) {
    __syncthreads();
#pragma unroll
    for (int i = 0; i < 2; ++i) {
      gload16(kstg + (size_t)(kb * 64 + i * 8) * 3072, &Ks[(w * 16 + i * 8) * 64]);
      gload16(vstg + (size_t)(i * 8) * 1024 + kb * 64, &Vs[(w * 16 + i * 8) * 64]);
    }
    __syncthreads();

    f32x4 s[4] = {};
#pragma unroll
    for (int t = 0; t < 4; ++t) {
      const int r = t * 16 + r16;
#pragma unroll
      for (int f = 0; f < 2; ++f) {
        const bf16x8 kf = *(const bf16x8*)&Ks[r * 64 + ((f * 4 + grp) ^ (r16 & 7)) * 8];
        s[t] = __builtin_amdgcn_mfma_f32_16x16x32_bf16(qf[f], kf, s[t], 0, 0, 0);
      }
    }
#pragma unroll
    for (int t = 0; t < 4; ++t)
#pragma unroll
      for (int r = 0; r < 4; ++r) {
        float v = s[t][r] * 0.125f;
        if (kb == qb && (t * 16 + r16) > (w * 16 + grp * 4 + r)) v = -1e30f;
        s[t][r] = v;
      }
    float fac[4];
#pragma unroll
    for (int r = 0; r < 4; ++r) {
      float mx = fmaxf(fmaxf(s[0][r], s[1][r]), fmaxf(s[2][r], s[3][r]));
#pragma unroll
      for (int msk = 1; msk < 16; msk <<= 1) mx = fmaxf(mx, __shfl_xor(mx, msk, 16));
      const float mn = fmaxf(mrow[r], mx);
      fac[r] = __expf(mrow[r] - mn);
      mrow[r] = mn;
      lsum[r] *= fac[r];
    }
#pragma unroll
    for (int t = 0; t < 4; ++t)
#pragma unroll
      for (int r = 0; r < 4; ++r) o[t][r] *= fac[r];
    float rsum[4] = {0.f, 0.f, 0.f, 0.f};
#pragma unroll
    for (int t = 0; t < 4; ++t)
#pragma unroll
      for (int r = 0; r < 4; ++r) {
        const float p = __expf(s[t][r] - mrow[r]);
        s[t][r] = p;
        rsum[r] += p;
      }
#pragma unroll
    for (int r = 0; r < 4; ++r) {
#pragma unroll
      for (int msk = 1; msk < 16; msk <<= 1) rsum[r] += __shfl_xor(rsum[r], msk, 16);
      lsum[r] += rsum[r];
    }
#pragma unroll
    for (int t = 0; t < 4; ++t)
#pragma unroll
      for (int r = 0; r < 4; ++r)
        Ps[w][grp * 4 + r][t * 16 + r16] = f2bf(s[t][r]);
    bf16x8 pf[2];
    pf[0] = *(const bf16x8*)&Ps[w][r16][grp * 8];
    pf[1] = *(const bf16x8*)&Ps[w][r16][32 + grp * 8];
#pragma unroll
    for (int t = 0; t < 4; ++t) {
      const int r = t * 16 + r16;
#pragma unroll
      for (int f = 0; f < 2; ++f) {
        const bf16x8 vf = *(const bf16x8*)&Vs[r * 64 + ((f * 4 + grp) ^ (r16 & 7)) * 8];
        o[t] = __builtin_amdgcn_mfma_f32_16x16x32_bf16(pf[f], vf, o[t], 0, 0, 0);
      }
    }
  }

  float inv[4];
#pragma unroll
  for (int r = 0; r < 4; ++r) inv[r] = 1.0f / lsum[r];
#pragma unroll
  for (int t = 0; t < 4; ++t)
#pragma unroll
    for (int r = 0; r < 4; ++r) {
      const int qrow = qb * 64 + w * 16 + grp * 4 + r;
      out[(rowbase + qrow) * 1024 + h * 64 + t * 16 + r16] = f2bf(o[t][r] * inv[r]);
    }
}

// ---------------- launch ----------------
extern "C" void kernel_launch(void* const* d_in, const int* in_sizes, int n_in,
                              void* d_out, int out_size, void* d_ws, size_t ws_size,
                              hipStream_t stream) {
  (void)in_sizes; (void)n_in; (void)out_size; (void)ws_size;
  const float* x     = (const float*)d_in[0];
  const float* ln1_g = (const float*)d_in[2];
  const float* ln1_b = (const float*)d_in[3];
  const float* wqkv  = (const float*)d_in[4];
  const float* bqkv  = (const float*)d_in[5];
  const float* wo    = (const float*)d_in[6];
  const float* bo    = (const float*)d_in[7];
  const float* ln2_g = (const float*)d_in[8];
  const float* ln2_b = (const float*)d_in[9];
  const float* w1    = (const float*)d_in[10];
  const float* b1    = (const float*)d_in[11];
  const float* w2    = (const float*)d_in[12];
  const float* b2    = (const float*)d_in[13];
  float* out = (float*)d_out;
  char* ws = (char*)d_ws;

  ushort* wqkvT = (ushort*)(ws + 0);          // [3072,1024] 6 MB
  ushort* woT   = (ushort*)(ws + 6291456);    // [1024,1024] 2 MB
  ushort* w1T   = (ushort*)(ws + 8388608);    // [4096,1024] 8 MB
  ushort* w2T   = (ushort*)(ws + 16777216);   // [1024,4096] 8 MB
  ushort* R1    = (ushort*)(ws + 25165824);   // 16 MB
  ushort* R2    = (ushort*)(ws + 41943040);   // 64 MB
  ushort* VT    = (ushort*)(ws + 41943040 + 50331648);  // 16 MB

  hipFuncSetAttribute(reinterpret_cast<const void*>(gemm256<0>),
                      hipFuncAttributeMaxDynamicSharedMemorySize, 131072);
  hipFuncSetAttribute(reinterpret_cast<const void*>(gemm256<1>),
                      hipFuncAttributeMaxDynamicSharedMemorySize, 131072);

  const dim3 blk(256);
  tcvt_kernel<<<dim3(3072 / 32, 1024 / 32), blk, 0, stream>>>(wqkv, wqkvT, 1024, 3072);
  tcvt_kernel<<<dim3(1024 / 32, 1024 / 32), blk, 0, stream>>>(wo, woT, 1024, 1024);
  tcvt_kernel<<<dim3(4096 / 32, 1024 / 32), blk, 0, stream>>>(w1, w1T, 1024, 4096);
  tcvt_kernel<<<dim3(1024 / 32, 4096 / 32), blk, 0, stream>>>(w2, w2T, 4096, 1024);

  ln_bf16_kernel<<<8192, blk, 0, stream>>>(x, ln1_g, ln1_b, R1);
  gemm256<0><<<dim3(3072 / 256, 8192 / 256), 512, 131072, stream>>>(R1, wqkvT, bqkv, R2, 8192, 3072, 1024);
  vtr_kernel<<<dim3(128, 16), blk, 0, stream>>>(R2, VT);
  attn_kernel<<<dim3(16, 128), blk, 0, stream>>>(R2, VT, R1);
  gemm_bf16<2><<<dim3(1024 / 128, 8192 / 128), blk, 0, stream>>>(R1, woT, bo, x, out, 8192, 1024, 1024);
  ln_bf16_kernel<<<8192, blk, 0, stream>>>(out, ln2_g, ln2_b, R1);
  gemm256<1><<<dim3(4096 / 256, 8192 / 256), 512, 131072, stream>>>(R1, w1T, b1, R2, 8192, 4096, 1024);
  gemm_bf16<2><<<dim3(1024 / 128, 8192 / 128), blk, 0, stream>>>(R2, w2T, b2, out, out, 8192, 1024, 4096);
}

// Round 11
// 567.072 us; speedup vs baseline: 1.0199x; 1.0199x over previous
//
#include <hip/hip_runtime.h>

// TransformerBlock: B=8, S=1024, D=1024, H=16, HD=64
// LN1 -> QKV GEMM(256q) -> causal flash attn (dbuf) -> proj(+resid,128q) -> LN2
//     -> MLP1(+gelu,256q) -> MLP2(+resid -> d_out,128q)
// 256q GEMM + attn: catalog-minimum 2-phase (sync -> stage t+1 -> compute t),
// global_load_lds(16B), both-sides XOR swizzle. No inline asm, no sched pinning.

#define DEV static __device__ __forceinline__

typedef __attribute__((ext_vector_type(8))) __bf16 bf16x8;
typedef __attribute__((ext_vector_type(4))) float f32x4;

DEV ushort f2bf(float f) {
  union { float f; unsigned u; } c; c.f = f;
  unsigned r = (c.u + 0x7FFFu + ((c.u >> 16) & 1u)) >> 16;
  return (ushort)r;
}

DEV float geluf(float v) {
  return 0.5f * v * (1.0f + erff(v * 0.70710678118654752f));
}

DEV void gload16(const ushort* g, ushort* l) {
  __builtin_amdgcn_global_load_lds(
      (const __attribute__((address_space(1))) void*)g,
      (__attribute__((address_space(3))) void*)l, 16, 0, 0);
}

// ---------------- LayerNorm (f32 in -> bf16 out), one block per row ----------------
__global__ __launch_bounds__(256)
void ln_bf16_kernel(const float* __restrict__ x, const float* __restrict__ g,
                    const float* __restrict__ bb, ushort* __restrict__ out)
{
  const int row = blockIdx.x, tid = threadIdx.x;
  const float4 v = ((const float4*)x)[row * 256 + tid];
  float s = v.x + v.y + v.z + v.w;
  float sq = v.x * v.x + v.y * v.y + v.z * v.z + v.w * v.w;
#pragma unroll
  for (int off = 32; off >= 1; off >>= 1) {
    s += __shfl_xor(s, off, 64);
    sq += __shfl_xor(sq, off, 64);
  }
  __shared__ float ps[4], pq[4];
  if ((tid & 63) == 0) { ps[tid >> 6] = s; pq[tid >> 6] = sq; }
  __syncthreads();
  s = ps[0] + ps[1] + ps[2] + ps[3];
  sq = pq[0] + pq[1] + pq[2] + pq[3];
  const float mu = s * (1.0f / 1024.0f);
  const float rstd = rsqrtf(sq * (1.0f / 1024.0f) - mu * mu + 1e-5f);
  const float4 gv = ((const float4*)g)[tid];
  const float4 bv = ((const float4*)bb)[tid];
  ushort4 o;
  o.x = f2bf((v.x - mu) * rstd * gv.x + bv.x);
  o.y = f2bf((v.y - mu) * rstd * gv.y + bv.y);
  o.z = f2bf((v.z - mu) * rstd * gv.z + bv.z);
  o.w = f2bf((v.w - mu) * rstd * gv.w + bv.w);
  ((ushort4*)out)[row * 256 + tid] = o;
}

// ---------------- transpose + f32->bf16: out[n*K+k] = bf16(in[k*N+n]) ----------------
__global__ __launch_bounds__(256)
void tcvt_kernel(const float* __restrict__ in, ushort* __restrict__ out, int K, int N)
{
  __shared__ float tile[32][33];
  const int tx = threadIdx.x & 31, ty = threadIdx.x >> 5;  // ty 0..7
  const int n0 = blockIdx.x * 32, k0 = blockIdx.y * 32;
#pragma unroll
  for (int j = 0; j < 4; ++j)
    tile[ty + j * 8][tx] = in[(size_t)(k0 + ty + j * 8) * N + n0 + tx];
  __syncthreads();
#pragma unroll
  for (int j = 0; j < 4; ++j)
    out[(size_t)(n0 + ty + j * 8) * K + k0 + tx] = f2bf(tile[tx][ty + j * 8]);
}

// ---------------- V^T extraction: VT[(bh*64+hd)*1024 + s] = qkv[b,s, 2048+h*64+hd] ----
__global__ __launch_bounds__(256)
void vtr_kernel(const ushort* __restrict__ qkv, ushort* __restrict__ VT)
{
  __shared__ ushort tile[64][72];
  const int tid = threadIdx.x;
  const int bh = blockIdx.x, sb = blockIdx.y;
  const int b = bh >> 4, h = bh & 15;
  const int s0 = sb * 64;
#pragma unroll
  for (int it = 0; it < 2; ++it) {
    const int idx = it * 256 + tid;
    const int r = idx >> 3, hc = (idx & 7) * 8;
    *(int4*)&tile[r][hc] =
        *(const int4*)(qkv + ((size_t)b * 1024 + s0 + r) * 3072 + 2048 + h * 64 + hc);
  }
  __syncthreads();
#pragma unroll
  for (int it = 0; it < 2; ++it) {
    const int idx = it * 256 + tid;
    const int hd = idx >> 3, sc = (idx & 7) * 8;
    union { int4 v; ushort u[8]; } o;
#pragma unroll
    for (int j = 0; j < 8; ++j) o.u[j] = tile[sc + j][hd];
    *(int4*)(VT + ((size_t)bh * 64 + hd) * 1024 + s0 + sc) = o.v;
  }
}

// ---------------- 128x128 GEMM (validated m97 structure) ----------------
// C[M,N] = A[M,K](bf16) * Bt[N,K]^T + bias (+epilogue). EPI 2: f32 out, +bias+resid.
template<int EPI>
__global__ __launch_bounds__(256)
void gemm_bf16(const ushort* __restrict__ A, const ushort* __restrict__ Bt,
               const float* __restrict__ bias, const float* __restrict__ resid,
               void* __restrict__ outp, int M, int N, int K)
{
  __shared__ ushort Asl[128 * 64];
  __shared__ ushort Bsl[128 * 64];
  const int tid = threadIdx.x;
  const int lane = tid & 63, w = tid >> 6;
  const int wm = w >> 1, wn = w & 1;
  const int grp = lane >> 4, r16 = lane & 15;
  const int bm = blockIdx.y * 128, bn = blockIdx.x * 128;

  const int lrow = lane >> 3;                      // 0..7
  const int uswz = ((lane & 7) ^ lrow) * 8;        // pre-swizzled k-unit (ushort offs)
  const ushort* pa = A  + (size_t)(bm + w * 32 + lrow) * K + uswz;
  const ushort* pb = Bt + (size_t)(bn + w * 32 + lrow) * K + uswz;

  f32x4 acc[4][4] = {};

  for (int k0 = 0; k0 < K; k0 += 64) {
    __syncthreads();
#pragma unroll
    for (int i = 0; i < 4; ++i) {
      gload16(pa + (size_t)(i * 8) * K + k0, &Asl[(w * 32 + i * 8) * 64]);
      gload16(pb + (size_t)(i * 8) * K + k0, &Bsl[(w * 32 + i * 8) * 64]);
    }
    __syncthreads();
#pragma unroll
    for (int ks = 0; ks < 2; ++ks) {
      bf16x8 af[4], bfr[4];
#pragma unroll
      for (int m = 0; m < 4; ++m) {
        const int r = wm * 64 + m * 16 + r16;
        af[m] = *(const bf16x8*)&Asl[r * 64 + ((ks * 4 + grp) ^ (r16 & 7)) * 8];
      }
#pragma unroll
      for (int n = 0; n < 4; ++n) {
        const int r = wn * 64 + n * 16 + r16;
        bfr[n] = *(const bf16x8*)&Bsl[r * 64 + ((ks * 4 + grp) ^ (r16 & 7)) * 8];
      }
#pragma unroll
      for (int m = 0; m < 4; ++m)
#pragma unroll
        for (int n = 0; n < 4; ++n)
          acc[m][n] = __builtin_amdgcn_mfma_f32_16x16x32_bf16(af[m], bfr[n], acc[m][n], 0, 0, 0);
    }
  }

#pragma unroll
  for (int n = 0; n < 4; ++n) {
    const int col = bn + wn * 64 + n * 16 + r16;
    const float bval = bias[col];
#pragma unroll
    for (int m = 0; m < 4; ++m) {
      const int row0 = bm + wm * 64 + m * 16 + grp * 4;
#pragma unroll
      for (int r = 0; r < 4; ++r) {
        const size_t idx = (size_t)(row0 + r) * N + col;
        float v = acc[m][n][r] + bval;
        if (EPI == 1) v = geluf(v);
        if (EPI == 2) ((float*)outp)[idx] = v + resid[idx];
        else          ((ushort*)outp)[idx] = f2bf(v);
      }
    }
  }
}

// ---------------- 256x256 GEMM, minimum-2-phase double-buffer ----------------
// 512 threads = 8 waves (2M x 4N), per-wave output 128x64, BK=64.
// LDS 128 KB dynamic: buf b at sm + b*32768 (A 16384 | B 16384 ushorts).
// Loop: sync (drains tile t, frees buf[(t+1)&1]) -> issue stage t+1 -> compute t.
// amdgpu_waves_per_eu(2,2): LDS caps us at 1 block/CU = 2 waves/SIMD; tell the
// register allocator so it doesn't strangle VGPRs chasing phantom occupancy.
template<int EPI>
__global__ __launch_bounds__(512) __attribute__((amdgpu_waves_per_eu(2, 2)))
void gemm256(const ushort* __restrict__ A, const ushort* __restrict__ Bt,
             const float* __restrict__ bias, void* __restrict__ outp,
             int M, int N, int K)
{
  extern __shared__ ushort sm[];                   // 2 * 32768 ushorts
  const int tid = threadIdx.x;
  const int lane = tid & 63, w = tid >> 6;         // wave 0..7
  const int wm = w >> 2, wn = w & 3;               // 2 x 4
  const int grp = lane >> 4, r16 = lane & 15;
  const int bm = blockIdx.y * 256, bn = blockIdx.x * 256;

  const int lrow = lane >> 3;                      // 0..7
  const int uswz = ((lane & 7) ^ lrow) * 8;        // pre-swizzled k-unit
  const ushort* pa = A  + (size_t)(bm + w * 32 + lrow) * K + uswz;
  const ushort* pb = Bt + (size_t)(bn + w * 32 + lrow) * K + uswz;

  const int nt = K >> 6;
  f32x4 acc[8][4] = {};

  // prologue: stage tile 0 into buf 0
#pragma unroll
  for (int i = 0; i < 4; ++i) {
    gload16(pa + (size_t)(i * 8) * K, &sm[(w * 32 + i * 8) * 64]);
    gload16(pb + (size_t)(i * 8) * K, &sm[16384 + (w * 32 + i * 8) * 64]);
  }

  for (int t = 0; t < nt; ++t) {
    __syncthreads();                               // tile t resident; buf[(t+1)&1] free
    if (t + 1 < nt) {
      const int k0 = (t + 1) * 64;
      ushort* za = sm + ((t + 1) & 1) * 32768;
#pragma unroll
      for (int i = 0; i < 4; ++i) {
        gload16(pa + (size_t)(i * 8) * K + k0, &za[(w * 32 + i * 8) * 64]);
        gload16(pb + (size_t)(i * 8) * K + k0, &za[16384 + (w * 32 + i * 8) * 64]);
      }
    }
    const ushort* as = sm + (t & 1) * 32768;
    const ushort* bs = as + 16384;
#pragma unroll
    for (int ks = 0; ks < 2; ++ks) {
      bf16x8 af[8], bfr[4];
#pragma unroll
      for (int mf = 0; mf < 8; ++mf) {
        const int r = wm * 128 + mf * 16 + r16;
        af[mf] = *(const bf16x8*)&as[r * 64 + ((ks * 4 + grp) ^ (r16 & 7)) * 8];
      }
#pragma unroll
      for (int nf = 0; nf < 4; ++nf) {
        const int r = wn * 64 + nf * 16 + r16;
        bfr[nf] = *(const bf16x8*)&bs[r * 64 + ((ks * 4 + grp) ^ (r16 & 7)) * 8];
      }
#pragma unroll
      for (int mf = 0; mf < 8; ++mf)
#pragma unroll
        for (int nf = 0; nf < 4; ++nf)
          acc[mf][nf] = __builtin_amdgcn_mfma_f32_16x16x32_bf16(af[mf], bfr[nf], acc[mf][nf], 0, 0, 0);
    }
  }

#pragma unroll
  for (int nf = 0; nf < 4; ++nf) {
    const int col = bn + wn * 64 + nf * 16 + r16;
    const float bval = bias[col];
#pragma unroll
    for (int mf = 0; mf < 8; ++mf) {
      const int row0 = bm + wm * 128 + mf * 16 + grp * 4;
#pragma unroll
      for (int r = 0; r < 4; ++r) {
        const size_t idx = (size_t)(row0 + r) * N + col;
        float v = acc[mf][nf][r] + bval;
        if (EPI == 1) v = geluf(v);
        ((ushort*)outp)[idx] = f2bf(v);
      }
    }
  }
}

// ---------------- Causal flash attention, minimum-2-phase double-buffer ----------------
// qkv: [B*S, 3*D] bf16; VT: [B*H*64, 1024] bf16; out: [B*S, D] bf16
// grid (16 q-blocks of 64, B*H). 4 waves; wave w owns q rows w*16..w*16+15.
// K/V^T tiles double-buffered: sync -> stage kb+1 -> compute kb (loads fly under compute).
__global__ __launch_bounds__(256)
void attn_kernel(const ushort* __restrict__ qkv, const ushort* __restrict__ VT,
                 ushort* __restrict__ out)
{
  __shared__ ushort Ks[2 * 64 * 64];
  __shared__ ushort Vs[2 * 64 * 64];
  __shared__ ushort Ps[4][16][72];
  const int tid = threadIdx.x, lane = tid & 63, w = tid >> 6;
  const int grp = lane >> 4, r16 = lane & 15;
  const int qb = 15 - blockIdx.x;    // heavy blocks first
  const int bh = blockIdx.y;
  const int b = bh >> 4, h = bh & 15;
  const size_t rowbase = (size_t)b * 1024;
  const int q0 = qb * 64 + w * 16;

  bf16x8 qf[2];
  {
    const ushort* qp = qkv + (rowbase + q0 + r16) * 3072 + h * 64;
    qf[0] = *(const bf16x8*)(qp + grp * 8);
    qf[1] = *(const bf16x8*)(qp + 32 + grp * 8);
  }

  const int lrow = lane >> 3;
  const int uswz = ((lane & 7) ^ lrow) * 8;
  const ushort* kstg = qkv + (rowbase + w * 16 + lrow) * 3072 + 1024 + h * 64 + uswz;
  const ushort* vstg = VT + ((size_t)bh * 64 + w * 16 + lrow) * 1024 + uswz;

  f32x4 o[4] = {};
  float mrow[4] = {-1e30f, -1e30f, -1e30f, -1e30f};
  float lsum[4] = {0.f, 0.f, 0.f, 0.f};

  // prologue: stage tile 0 into buf 0
#pragma unroll
  for (int i = 0; i < 2; ++i) {
    gload16(kstg + (size_t)(i * 8) * 3072, &Ks[(w * 16 + i * 8) * 64]);
    gload16(vstg + (size_t)(i * 8) * 1024, &Vs[(w * 16 + i * 8) * 64]);
  }

  for (int kb = 0; kb <= qb; ++kb) {
    __syncthreads();                 // tile kb resident; buf[(kb+1)&1] free
    if (kb < qb) {
      const int nb = (kb + 1) & 1;
#pragma unroll
      for (int i = 0; i < 2; ++i) {
        gload16(kstg + (size_t)((kb + 1) * 64 + i * 8) * 3072, &Ks[nb * 4096 + (w * 16 + i * 8) * 64]);
        gload16(vstg + (size_t)(i * 8) * 1024 + (kb + 1) * 64, &Vs[nb * 4096 + (w * 16 + i * 8) * 64]);
      }
    }
    const ushort* Kb = Ks + (kb & 1) * 4096;
    const ushort* Vb = Vs + (kb & 1) * 4096;

    // S = Q K^T  (B-fragment: col j = kv = t*16+r16, k = hd)
    f32x4 s[4] = {};
#pragma unroll
    for (int t = 0; t < 4; ++t) {
      const int r = t * 16 + r16;
#pragma unroll
      for (int f = 0; f < 2; ++f) {
        const bf16x8 kf = *(const bf16x8*)&Kb[r * 64 + ((f * 4 + grp) ^ (r16 & 7)) * 8];
        s[t] = __builtin_amdgcn_mfma_f32_16x16x32_bf16(qf[f], kf, s[t], 0, 0, 0);
      }
    }
    // scale + causal mask (diagonal block only)
#pragma unroll
    for (int t = 0; t < 4; ++t)
#pragma unroll
      for (int r = 0; r < 4; ++r) {
        float v = s[t][r] * 0.125f;
        if (kb == qb && (t * 16 + r16) > (w * 16 + grp * 4 + r)) v = -1e30f;
        s[t][r] = v;
      }
    // online softmax (row r lives on the 16 lanes sharing grp)
    float fac[4];
#pragma unroll
    for (int r = 0; r < 4; ++r) {
      float mx = fmaxf(fmaxf(s[0][r], s[1][r]), fmaxf(s[2][r], s[3][r]));
#pragma unroll
      for (int msk = 1; msk < 16; msk <<= 1) mx = fmaxf(mx, __shfl_xor(mx, msk, 16));
      const float mn = fmaxf(mrow[r], mx);
      fac[r] = __expf(mrow[r] - mn);
      mrow[r] = mn;
      lsum[r] *= fac[r];
    }
#pragma unroll
    for (int t = 0; t < 4; ++t)
#pragma unroll
      for (int r = 0; r < 4; ++r) o[t][r] *= fac[r];
    float rsum[4] = {0.f, 0.f, 0.f, 0.f};
#pragma unroll
    for (int t = 0; t < 4; ++t)
#pragma unroll
      for (int r = 0; r < 4; ++r) {
        const float p = __expf(s[t][r] - mrow[r]);
        s[t][r] = p;
        rsum[r] += p;
      }
#pragma unroll
    for (int r = 0; r < 4; ++r) {
#pragma unroll
      for (int msk = 1; msk < 16; msk <<= 1) rsum[r] += __shfl_xor(rsum[r], msk, 16);
      lsum[r] += rsum[r];
    }
    // P: C-layout -> A-fragment layout round trip (per-wave LDS, in-order within wave)
#pragma unroll
    for (int t = 0; t < 4; ++t)
#pragma unroll
      for (int r = 0; r < 4; ++r)
        Ps[w][grp * 4 + r][t * 16 + r16] = f2bf(s[t][r]);
    bf16x8 pf[2];
    pf[0] = *(const bf16x8*)&Ps[w][r16][grp * 8];
    pf[1] = *(const bf16x8*)&Ps[w][r16][32 + grp * 8];
    // O += P V  (B-fragment: col j = hd = t*16+r16, k = kv)
#pragma unroll
    for (int t = 0; t < 4; ++t) {
      const int r = t * 16 + r16;
#pragma unroll
      for (int f = 0; f < 2; ++f) {
        const bf16x8 vf = *(const bf16x8*)&Vb[r * 64 + ((f * 4 + grp) ^ (r16 & 7)) * 8];
        o[t] = __builtin_amdgcn_mfma_f32_16x16x32_bf16(pf[f], vf, o[t], 0, 0, 0);
      }
    }
  }

  float inv[4];
#pragma unroll
  for (int r = 0; r < 4; ++r) inv[r] = 1.0f / lsum[r];
#pragma unroll
  for (int t = 0; t < 4; ++t)
#pragma unroll
    for (int r = 0; r < 4; ++r) {
      const int qrow = qb * 64 + w * 16 + grp * 4 + r;
      out[(rowbase + qrow) * 1024 + h * 64 + t * 16 + r16] = f2bf(o[t][r] * inv[r]);
    }
}

// ---------------- launch ----------------
extern "C" void kernel_launch(void* const* d_in, const int* in_sizes, int n_in,
                              void* d_out, int out_size, void* d_ws, size_t ws_size,
                              hipStream_t stream) {
  (void)in_sizes; (void)n_in; (void)out_size; (void)ws_size;
  const float* x     = (const float*)d_in[0];
  const float* ln1_g = (const float*)d_in[2];
  const float* ln1_b = (const float*)d_in[3];
  const float* wqkv  = (const float*)d_in[4];
  const float* bqkv  = (const float*)d_in[5];
  const float* wo    = (const float*)d_in[6];
  const float* bo    = (const float*)d_in[7];
  const float* ln2_g = (const float*)d_in[8];
  const float* ln2_b = (const float*)d_in[9];
  const float* w1    = (const float*)d_in[10];
  const float* b1    = (const float*)d_in[11];
  const float* w2    = (const float*)d_in[12];
  const float* b2    = (const float*)d_in[13];
  float* out = (float*)d_out;
  char* ws = (char*)d_ws;

  ushort* wqkvT = (ushort*)(ws + 0);          // [3072,1024] 6 MB
  ushort* woT   = (ushort*)(ws + 6291456);    // [1024,1024] 2 MB
  ushort* w1T   = (ushort*)(ws + 8388608);    // [4096,1024] 8 MB
  ushort* w2T   = (ushort*)(ws + 16777216);   // [1024,4096] 8 MB
  ushort* R1    = (ushort*)(ws + 25165824);   // 16 MB
  ushort* R2    = (ushort*)(ws + 41943040);   // 64 MB
  ushort* VT    = (ushort*)(ws + 41943040 + 50331648);  // 16 MB

  hipFuncSetAttribute(reinterpret_cast<const void*>(gemm256<0>),
                      hipFuncAttributeMaxDynamicSharedMemorySize, 131072);
  hipFuncSetAttribute(reinterpret_cast<const void*>(gemm256<1>),
                      hipFuncAttributeMaxDynamicSharedMemorySize, 131072);

  const dim3 blk(256);
  tcvt_kernel<<<dim3(3072 / 32, 1024 / 32), blk, 0, stream>>>(wqkv, wqkvT, 1024, 3072);
  tcvt_kernel<<<dim3(1024 / 32, 1024 / 32), blk, 0, stream>>>(wo, woT, 1024, 1024);
  tcvt_kernel<<<dim3(4096 / 32, 1024 / 32), blk, 0, stream>>>(w1, w1T, 1024, 4096);
  tcvt_kernel<<<dim3(1024 / 32, 4096 / 32), blk, 0, stream>>>(w2, w2T, 4096, 1024);

  ln_bf16_kernel<<<8192, blk, 0, stream>>>(x, ln1_g, ln1_b, R1);
  gemm256<0><<<dim3(3072 / 256, 8192 / 256), 512, 131072, stream>>>(R1, wqkvT, bqkv, R2, 8192, 3072, 1024);
  vtr_kernel<<<dim3(128, 16), blk, 0, stream>>>(R2, VT);
  attn_kernel<<<dim3(16, 128), blk, 0, stream>>>(R2, VT, R1);
  gemm_bf16<2><<<dim3(1024 / 128, 8192 / 128), blk, 0, stream>>>(R1, woT, bo, x, out, 8192, 1024, 1024);
  ln_bf16_kernel<<<8192, blk, 0, stream>>>(out, ln2_g, ln2_b, R1);
  gemm256<1><<<dim3(4096 / 256, 8192 / 256), 512, 131072, stream>>>(R1, w1T, b1, R2, 8192, 4096, 1024);
  gemm_bf16<2><<<dim3(1024 / 128, 8192 / 128), blk, 0, stream>>>(R2, w2T, b2, out, out, 8192, 1024, 4096);
}

// Round 13
// 551.766 us; speedup vs baseline: 1.0482x; 1.0277x over previous
//
#include <hip/hip_runtime.h>

// TransformerBlock: B=8, S=1024, D=1024, H=16, HD=64
// LN1 -> QKV GEMM(256q) -> causal flash attn (dbuf) -> proj(+resid,128q) -> LN2
//     -> MLP1(+gelu,256q) -> MLP2(+resid -> d_out,128q)
// 256q GEMM + attn: catalog-minimum 2-phase (sync -> stage t+1 -> compute t),
// global_load_lds(16B), both-sides XOR swizzle. Epilogue: nf-inner (row-contiguous
// 128B bursts) to avoid partial-line L2 writebacks.

#define DEV static __device__ __forceinline__

typedef __attribute__((ext_vector_type(8))) __bf16 bf16x8;
typedef __attribute__((ext_vector_type(4))) float f32x4;

DEV ushort f2bf(float f) {
  union { float f; unsigned u; } c; c.f = f;
  unsigned r = (c.u + 0x7FFFu + ((c.u >> 16) & 1u)) >> 16;
  return (ushort)r;
}

DEV float geluf(float v) {
  return 0.5f * v * (1.0f + erff(v * 0.70710678118654752f));
}

DEV void gload16(const ushort* g, ushort* l) {
  __builtin_amdgcn_global_load_lds(
      (const __attribute__((address_space(1))) void*)g,
      (__attribute__((address_space(3))) void*)l, 16, 0, 0);
}

// ---------------- LayerNorm (f32 in -> bf16 out), one block per row ----------------
__global__ __launch_bounds__(256)
void ln_bf16_kernel(const float* __restrict__ x, const float* __restrict__ g,
                    const float* __restrict__ bb, ushort* __restrict__ out)
{
  const int row = blockIdx.x, tid = threadIdx.x;
  const float4 v = ((const float4*)x)[row * 256 + tid];
  float s = v.x + v.y + v.z + v.w;
  float sq = v.x * v.x + v.y * v.y + v.z * v.z + v.w * v.w;
#pragma unroll
  for (int off = 32; off >= 1; off >>= 1) {
    s += __shfl_xor(s, off, 64);
    sq += __shfl_xor(sq, off, 64);
  }
  __shared__ float ps[4], pq[4];
  if ((tid & 63) == 0) { ps[tid >> 6] = s; pq[tid >> 6] = sq; }
  __syncthreads();
  s = ps[0] + ps[1] + ps[2] + ps[3];
  sq = pq[0] + pq[1] + pq[2] + pq[3];
  const float mu = s * (1.0f / 1024.0f);
  const float rstd = rsqrtf(sq * (1.0f / 1024.0f) - mu * mu + 1e-5f);
  const float4 gv = ((const float4*)g)[tid];
  const float4 bv = ((const float4*)bb)[tid];
  ushort4 o;
  o.x = f2bf((v.x - mu) * rstd * gv.x + bv.x);
  o.y = f2bf((v.y - mu) * rstd * gv.y + bv.y);
  o.z = f2bf((v.z - mu) * rstd * gv.z + bv.z);
  o.w = f2bf((v.w - mu) * rstd * gv.w + bv.w);
  ((ushort4*)out)[row * 256 + tid] = o;
}

// ---------------- transpose + f32->bf16: out[n*K+k] = bf16(in[k*N+n]) ----------------
__global__ __launch_bounds__(256)
void tcvt_kernel(const float* __restrict__ in, ushort* __restrict__ out, int K, int N)
{
  __shared__ float tile[32][33];
  const int tx = threadIdx.x & 31, ty = threadIdx.x >> 5;  // ty 0..7
  const int n0 = blockIdx.x * 32, k0 = blockIdx.y * 32;
#pragma unroll
  for (int j = 0; j < 4; ++j)
    tile[ty + j * 8][tx] = in[(size_t)(k0 + ty + j * 8) * N + n0 + tx];
  __syncthreads();
#pragma unroll
  for (int j = 0; j < 4; ++j)
    out[(size_t)(n0 + ty + j * 8) * K + k0 + tx] = f2bf(tile[tx][ty + j * 8]);
}

// ---------------- V^T extraction: VT[(bh*64+hd)*1024 + s] = qkv[b,s, 2048+h*64+hd] ----
__global__ __launch_bounds__(256)
void vtr_kernel(const ushort* __restrict__ qkv, ushort* __restrict__ VT)
{
  __shared__ ushort tile[64][72];
  const int tid = threadIdx.x;
  const int bh = blockIdx.x, sb = blockIdx.y;
  const int b = bh >> 4, h = bh & 15;
  const int s0 = sb * 64;
#pragma unroll
  for (int it = 0; it < 2; ++it) {
    const int idx = it * 256 + tid;
    const int r = idx >> 3, hc = (idx & 7) * 8;
    *(int4*)&tile[r][hc] =
        *(const int4*)(qkv + ((size_t)b * 1024 + s0 + r) * 3072 + 2048 + h * 64 + hc);
  }
  __syncthreads();
#pragma unroll
  for (int it = 0; it < 2; ++it) {
    const int idx = it * 256 + tid;
    const int hd = idx >> 3, sc = (idx & 7) * 8;
    union { int4 v; ushort u[8]; } o;
#pragma unroll
    for (int j = 0; j < 8; ++j) o.u[j] = tile[sc + j][hd];
    *(int4*)(VT + ((size_t)bh * 64 + hd) * 1024 + s0 + sc) = o.v;
  }
}

// ---------------- 128x128 GEMM (validated m97 structure) ----------------
// C[M,N] = A[M,K](bf16) * Bt[N,K]^T + bias (+epilogue). EPI 2: f32 out, +bias+resid.
template<int EPI>
__global__ __launch_bounds__(256)
void gemm_bf16(const ushort* __restrict__ A, const ushort* __restrict__ Bt,
               const float* __restrict__ bias, const float* __restrict__ resid,
               void* __restrict__ outp, int M, int N, int K)
{
  __shared__ ushort Asl[128 * 64];
  __shared__ ushort Bsl[128 * 64];
  const int tid = threadIdx.x;
  const int lane = tid & 63, w = tid >> 6;
  const int wm = w >> 1, wn = w & 1;
  const int grp = lane >> 4, r16 = lane & 15;
  const int bm = blockIdx.y * 128, bn = blockIdx.x * 128;

  const int lrow = lane >> 3;                      // 0..7
  const int uswz = ((lane & 7) ^ lrow) * 8;        // pre-swizzled k-unit (ushort offs)
  const ushort* pa = A  + (size_t)(bm + w * 32 + lrow) * K + uswz;
  const ushort* pb = Bt + (size_t)(bn + w * 32 + lrow) * K + uswz;

  f32x4 acc[4][4] = {};

  for (int k0 = 0; k0 < K; k0 += 64) {
    __syncthreads();
#pragma unroll
    for (int i = 0; i < 4; ++i) {
      gload16(pa + (size_t)(i * 8) * K + k0, &Asl[(w * 32 + i * 8) * 64]);
      gload16(pb + (size_t)(i * 8) * K + k0, &Bsl[(w * 32 + i * 8) * 64]);
    }
    __syncthreads();
#pragma unroll
    for (int ks = 0; ks < 2; ++ks) {
      bf16x8 af[4], bfr[4];
#pragma unroll
      for (int m = 0; m < 4; ++m) {
        const int r = wm * 64 + m * 16 + r16;
        af[m] = *(const bf16x8*)&Asl[r * 64 + ((ks * 4 + grp) ^ (r16 & 7)) * 8];
      }
#pragma unroll
      for (int n = 0; n < 4; ++n) {
        const int r = wn * 64 + n * 16 + r16;
        bfr[n] = *(const bf16x8*)&Bsl[r * 64 + ((ks * 4 + grp) ^ (r16 & 7)) * 8];
      }
#pragma unroll
      for (int m = 0; m < 4; ++m)
#pragma unroll
        for (int n = 0; n < 4; ++n)
          acc[m][n] = __builtin_amdgcn_mfma_f32_16x16x32_bf16(af[m], bfr[n], acc[m][n], 0, 0, 0);
    }
  }

#pragma unroll
  for (int n = 0; n < 4; ++n) {
    const int col = bn + wn * 64 + n * 16 + r16;
    const float bval = bias[col];
#pragma unroll
    for (int m = 0; m < 4; ++m) {
      const int row0 = bm + wm * 64 + m * 16 + grp * 4;
#pragma unroll
      for (int r = 0; r < 4; ++r) {
        const size_t idx = (size_t)(row0 + r) * N + col;
        float v = acc[m][n][r] + bval;
        if (EPI == 1) v = geluf(v);
        if (EPI == 2) ((float*)outp)[idx] = v + resid[idx];
        else          ((ushort*)outp)[idx] = f2bf(v);
      }
    }
  }
}

// ---------------- 256x256 GEMM, minimum-2-phase double-buffer ----------------
// 512 threads = 8 waves (2M x 4N), per-wave output 128x64, BK=64.
// LDS 128 KB dynamic: buf b at sm + b*32768 (A 16384 | B 16384 ushorts).
// Loop: sync (drains tile t, frees buf[(t+1)&1]) -> issue stage t+1 -> compute t.
// Epilogue: nf INNERMOST so each output row's four 32B segments are issued
// back-to-back (128B contiguous per wave-row) -> full-line L2 writebacks.
template<int EPI>
__global__ __launch_bounds__(512) __attribute__((amdgpu_waves_per_eu(2, 2)))
void gemm256(const ushort* __restrict__ A, const ushort* __restrict__ Bt,
             const float* __restrict__ bias, void* __restrict__ outp,
             int M, int N, int K)
{
  extern __shared__ ushort sm[];                   // 2 * 32768 ushorts
  const int tid = threadIdx.x;
  const int lane = tid & 63, w = tid >> 6;         // wave 0..7
  const int wm = w >> 2, wn = w & 3;               // 2 x 4
  const int grp = lane >> 4, r16 = lane & 15;
  const int bm = blockIdx.y * 256, bn = blockIdx.x * 256;

  const int lrow = lane >> 3;                      // 0..7
  const int uswz = ((lane & 7) ^ lrow) * 8;        // pre-swizzled k-unit
  const ushort* pa = A  + (size_t)(bm + w * 32 + lrow) * K + uswz;
  const ushort* pb = Bt + (size_t)(bn + w * 32 + lrow) * K + uswz;

  const int nt = K >> 6;
  f32x4 acc[8][4] = {};

  // prologue: stage tile 0 into buf 0
#pragma unroll
  for (int i = 0; i < 4; ++i) {
    gload16(pa + (size_t)(i * 8) * K, &sm[(w * 32 + i * 8) * 64]);
    gload16(pb + (size_t)(i * 8) * K, &sm[16384 + (w * 32 + i * 8) * 64]);
  }

  for (int t = 0; t < nt; ++t) {
    __syncthreads();                               // tile t resident; buf[(t+1)&1] free
    if (t + 1 < nt) {
      const int k0 = (t + 1) * 64;
      ushort* za = sm + ((t + 1) & 1) * 32768;
#pragma unroll
      for (int i = 0; i < 4; ++i) {
        gload16(pa + (size_t)(i * 8) * K + k0, &za[(w * 32 + i * 8) * 64]);
        gload16(pb + (size_t)(i * 8) * K + k0, &za[16384 + (w * 32 + i * 8) * 64]);
      }
    }
    const ushort* as = sm + (t & 1) * 32768;
    const ushort* bs = as + 16384;
#pragma unroll
    for (int ks = 0; ks < 2; ++ks) {
      bf16x8 af[8], bfr[4];
#pragma unroll
      for (int mf = 0; mf < 8; ++mf) {
        const int r = wm * 128 + mf * 16 + r16;
        af[mf] = *(const bf16x8*)&as[r * 64 + ((ks * 4 + grp) ^ (r16 & 7)) * 8];
      }
#pragma unroll
      for (int nf = 0; nf < 4; ++nf) {
        const int r = wn * 64 + nf * 16 + r16;
        bfr[nf] = *(const bf16x8*)&bs[r * 64 + ((ks * 4 + grp) ^ (r16 & 7)) * 8];
      }
#pragma unroll
      for (int mf = 0; mf < 8; ++mf)
#pragma unroll
        for (int nf = 0; nf < 4; ++nf)
          acc[mf][nf] = __builtin_amdgcn_mfma_f32_16x16x32_bf16(af[mf], bfr[nf], acc[mf][nf], 0, 0, 0);
    }
  }

  // epilogue: per-row contiguous bursts (nf inner)
  float bv[4];
#pragma unroll
  for (int nf = 0; nf < 4; ++nf) bv[nf] = bias[bn + wn * 64 + nf * 16 + r16];
#pragma unroll
  for (int mf = 0; mf < 8; ++mf) {
#pragma unroll
    for (int r = 0; r < 4; ++r) {
      const size_t row = (size_t)(bm + wm * 128 + mf * 16 + grp * 4 + r);
      ushort* orow = (ushort*)outp + row * N + bn + wn * 64 + r16;
#pragma unroll
      for (int nf = 0; nf < 4; ++nf) {
        float v = acc[mf][nf][r] + bv[nf];
        if (EPI == 1) v = geluf(v);
        orow[nf * 16] = f2bf(v);
      }
    }
  }
}

// ---------------- Causal flash attention, minimum-2-phase double-buffer ----------------
// qkv: [B*S, 3*D] bf16; VT: [B*H*64, 1024] bf16; out: [B*S, D] bf16
// grid (16 q-blocks of 64, B*H). 4 waves; wave w owns q rows w*16..w*16+15.
// K/V^T tiles double-buffered: sync -> stage kb+1 -> compute kb (loads fly under compute).
__global__ __launch_bounds__(256)
void attn_kernel(const ushort* __restrict__ qkv, const ushort* __restrict__ VT,
                 ushort* __restrict__ out)
{
  __shared__ ushort Ks[2 * 64 * 64];
  __shared__ ushort Vs[2 * 64 * 64];
  __shared__ ushort Ps[4][16][72];
  const int tid = threadIdx.x, lane = tid & 63, w = tid >> 6;
  const int grp = lane >> 4, r16 = lane & 15;
  const int qb = 15 - blockIdx.x;    // heavy blocks first
  const int bh = blockIdx.y;
  const int b = bh >> 4, h = bh & 15;
  const size_t rowbase = (size_t)b * 1024;
  const int q0 = qb * 64 + w * 16;

  bf16x8 qf[2];
  {
    const ushort* qp = qkv + (rowbase + q0 + r16) * 3072 + h * 64;
    qf[0] = *(const bf16x8*)(qp + grp * 8);
    qf[1] = *(const bf16x8*)(qp + 32 + grp * 8);
  }

  const int lrow = lane >> 3;
  const int uswz = ((lane & 7) ^ lrow) * 8;
  const ushort* kstg = qkv + (rowbase + w * 16 + lrow) * 3072 + 1024 + h * 64 + uswz;
  const ushort* vstg = VT + ((size_t)bh * 64 + w * 16 + lrow) * 1024 + uswz;

  f32x4 o[4] = {};
  float mrow[4] = {-1e30f, -1e30f, -1e30f, -1e30f};
  float lsum[4] = {0.f, 0.f, 0.f, 0.f};

  // prologue: stage tile 0 into buf 0
#pragma unroll
  for (int i = 0; i < 2; ++i) {
    gload16(kstg + (size_t)(i * 8) * 3072, &Ks[(w * 16 + i * 8) * 64]);
    gload16(vstg + (size_t)(i * 8) * 1024, &Vs[(w * 16 + i * 8) * 64]);
  }

  for (int kb = 0; kb <= qb; ++kb) {
    __syncthreads();                 // tile kb resident; buf[(kb+1)&1] free
    if (kb < qb) {
      const int nb = (kb + 1) & 1;
#pragma unroll
      for (int i = 0; i < 2; ++i) {
        gload16(kstg + (size_t)((kb + 1) * 64 + i * 8) * 3072, &Ks[nb * 4096 + (w * 16 + i * 8) * 64]);
        gload16(vstg + (size_t)(i * 8) * 1024 + (kb + 1) * 64, &Vs[nb * 4096 + (w * 16 + i * 8) * 64]);
      }
    }
    const ushort* Kb = Ks + (kb & 1) * 4096;
    const ushort* Vb = Vs + (kb & 1) * 4096;

    // S = Q K^T  (B-fragment: col j = kv = t*16+r16, k = hd)
    f32x4 s[4] = {};
#pragma unroll
    for (int t = 0; t < 4; ++t) {
      const int r = t * 16 + r16;
#pragma unroll
      for (int f = 0; f < 2; ++f) {
        const bf16x8 kf = *(const bf16x8*)&Kb[r * 64 + ((f * 4 + grp) ^ (r16 & 7)) * 8];
        s[t] = __builtin_amdgcn_mfma_f32_16x16x32_bf16(qf[f], kf, s[t], 0, 0, 0);
      }
    }
    // scale + causal mask (diagonal block only)
#pragma unroll
    for (int t = 0; t < 4; ++t)
#pragma unroll
      for (int r = 0; r < 4; ++r) {
        float v = s[t][r] * 0.125f;
        if (kb == qb && (t * 16 + r16) > (w * 16 + grp * 4 + r)) v = -1e30f;
        s[t][r] = v;
      }
    // online softmax (row r lives on the 16 lanes sharing grp)
    float fac[4];
#pragma unroll
    for (int r = 0; r < 4; ++r) {
      float mx = fmaxf(fmaxf(s[0][r], s[1][r]), fmaxf(s[2][r], s[3][r]));
#pragma unroll
      for (int msk = 1; msk < 16; msk <<= 1) mx = fmaxf(mx, __shfl_xor(mx, msk, 16));
      const float mn = fmaxf(mrow[r], mx);
      fac[r] = __expf(mrow[r] - mn);
      mrow[r] = mn;
      lsum[r] *= fac[r];
    }
#pragma unroll
    for (int t = 0; t < 4; ++t)
#pragma unroll
      for (int r = 0; r < 4; ++r) o[t][r] *= fac[r];
    float rsum[4] = {0.f, 0.f, 0.f, 0.f};
#pragma unroll
    for (int t = 0; t < 4; ++t)
#pragma unroll
      for (int r = 0; r < 4; ++r) {
        const float p = __expf(s[t][r] - mrow[r]);
        s[t][r] = p;
        rsum[r] += p;
      }
#pragma unroll
    for (int r = 0; r < 4; ++r) {
#pragma unroll
      for (int msk = 1; msk < 16; msk <<= 1) rsum[r] += __shfl_xor(rsum[r], msk, 16);
      lsum[r] += rsum[r];
    }
    // P: C-layout -> A-fragment layout round trip (per-wave LDS, in-order within wave)
#pragma unroll
    for (int t = 0; t < 4; ++t)
#pragma unroll
      for (int r = 0; r < 4; ++r)
        Ps[w][grp * 4 + r][t * 16 + r16] = f2bf(s[t][r]);
    bf16x8 pf[2];
    pf[0] = *(const bf16x8*)&Ps[w][r16][grp * 8];
    pf[1] = *(const bf16x8*)&Ps[w][r16][32 + grp * 8];
    // O += P V  (B-fragment: col j = hd = t*16+r16, k = kv)
#pragma unroll
    for (int t = 0; t < 4; ++t) {
      const int r = t * 16 + r16;
#pragma unroll
      for (int f = 0; f < 2; ++f) {
        const bf16x8 vf = *(const bf16x8*)&Vb[r * 64 + ((f * 4 + grp) ^ (r16 & 7)) * 8];
        o[t] = __builtin_amdgcn_mfma_f32_16x16x32_bf16(pf[f], vf, o[t], 0, 0, 0);
      }
    }
  }

  float inv[4];
#pragma unroll
  for (int r = 0; r < 4; ++r) inv[r] = 1.0f / lsum[r];
#pragma unroll
  for (int t = 0; t < 4; ++t)
#pragma unroll
    for (int r = 0; r < 4; ++r) {
      const int qrow = qb * 64 + w * 16 + grp * 4 + r;
      out[(rowbase + qrow) * 1024 + h * 64 + t * 16 + r16] = f2bf(o[t][r] * inv[r]);
    }
}

// ---------------- launch ----------------
extern "C" void kernel_launch(void* const* d_in, const int* in_sizes, int n_in,
                              void* d_out, int out_size, void* d_ws, size_t ws_size,
                              hipStream_t stream) {
  (void)in_sizes; (void)n_in; (void)out_size; (void)ws_size;
  const float* x     = (const float*)d_in[0];
  const float* ln1_g = (const float*)d_in[2];
  const float* ln1_b = (const float*)d_in[3];
  const float* wqkv  = (const float*)d_in[4];
  const float* bqkv  = (const float*)d_in[5];
  const float* wo    = (const float*)d_in[6];
  const float* bo    = (const float*)d_in[7];
  const float* ln2_g = (const float*)d_in[8];
  const float* ln2_b = (const float*)d_in[9];
  const float* w1    = (const float*)d_in[10];
  const float* b1    = (const float*)d_in[11];
  const float* w2    = (const float*)d_in[12];
  const float* b2    = (const float*)d_in[13];
  float* out = (float*)d_out;
  char* ws = (char*)d_ws;

  ushort* wqkvT = (ushort*)(ws + 0);          // [3072,1024] 6 MB
  ushort* woT   = (ushort*)(ws + 6291456);    // [1024,1024] 2 MB
  ushort* w1T   = (ushort*)(ws + 8388608);    // [4096,1024] 8 MB
  ushort* w2T   = (ushort*)(ws + 16777216);   // [1024,4096] 8 MB
  ushort* R1    = (ushort*)(ws + 25165824);   // 16 MB
  ushort* R2    = (ushort*)(ws + 41943040);   // 64 MB
  ushort* VT    = (ushort*)(ws + 41943040 + 50331648);  // 16 MB

  hipFuncSetAttribute(reinterpret_cast<const void*>(gemm256<0>),
                      hipFuncAttributeMaxDynamicSharedMemorySize, 131072);
  hipFuncSetAttribute(reinterpret_cast<const void*>(gemm256<1>),
                      hipFuncAttributeMaxDynamicSharedMemorySize, 131072);

  const dim3 blk(256);
  tcvt_kernel<<<dim3(3072 / 32, 1024 / 32), blk, 0, stream>>>(wqkv, wqkvT, 1024, 3072);
  tcvt_kernel<<<dim3(1024 / 32, 1024 / 32), blk, 0, stream>>>(wo, woT, 1024, 1024);
  tcvt_kernel<<<dim3(4096 / 32, 1024 / 32), blk, 0, stream>>>(w1, w1T, 1024, 4096);
  tcvt_kernel<<<dim3(1024 / 32, 4096 / 32), blk, 0, stream>>>(w2, w2T, 4096, 1024);

  ln_bf16_kernel<<<8192, blk, 0, stream>>>(x, ln1_g, ln1_b, R1);
  gemm256<0><<<dim3(3072 / 256, 8192 / 256), 512, 131072, stream>>>(R1, wqkvT, bqkv, R2, 8192, 3072, 1024);
  vtr_kernel<<<dim3(128, 16), blk, 0, stream>>>(R2, VT);
  attn_kernel<<<dim3(16, 128), blk, 0, stream>>>(R2, VT, R1);
  gemm_bf16<2><<<dim3(1024 / 128, 8192 / 128), blk, 0, stream>>>(R1, woT, bo, x, out, 8192, 1024, 1024);
  ln_bf16_kernel<<<8192, blk, 0, stream>>>(out, ln2_g, ln2_b, R1);
  gemm256<1><<<dim3(4096 / 256, 8192 / 256), 512, 131072, stream>>>(R1, w1T, b1, R2, 8192, 4096, 1024);
  gemm_bf16<2><<<dim3(1024 / 128, 8192 / 128), blk, 0, stream>>>(R2, w2T, b2, out, out, 8192, 1024, 4096);
}